// Round 19
// baseline (207.549 us; speedup 1.0000x reference)
//
#include <hip/hip_runtime.h>

typedef unsigned short u16;
typedef unsigned int   u32;
typedef __attribute__((ext_vector_type(8))) short bf16x8;
typedef __attribute__((ext_vector_type(4))) float f32x4;

// ---------- bf16 helpers (manual, RNE) ----------
__device__ __forceinline__ u16 f2bf(float f) {
    u32 u = __float_as_uint(f);
    u += 0x7fffu + ((u >> 16) & 1u);
    return (u16)(u >> 16);
}
__device__ __forceinline__ float bf2f(u16 s) {
    return __uint_as_float(((u32)s) << 16);
}
__device__ __forceinline__ u32 pack2bf(float f0, float f1) {
    return (u32)f2bf(f0) | ((u32)f2bf(f1) << 16);
}
// HW packed conversion (validated on P/ctx/x-iterate paths only — NOT
// upstream of the exp(10*cos-10) amplifier; see R13 post-mortem)
__device__ __forceinline__ u32 cvtpk2bf(float f0, float f1) {
    u32 r;
    asm("v_cvt_pk_bf16_f32 %0, %1, %2" : "=v"(r) : "v"(f0), "v"(f1));
    return r;
}

__device__ __forceinline__ void gload_lds16(const void* g, void* l) {
    __builtin_amdgcn_global_load_lds(
        (const __attribute__((address_space(1))) u32*)g,
        (__attribute__((address_space(3))) u32*)l, 16, 0, 0);
}

// =======================================================================
// Fused fp32 -> bf16 conversion for ALL three inputs (one launch).
// =======================================================================
__global__ __launch_bounds__(256)
void conv_all(const float* __restrict__ x, const float* __restrict__ wqkv,
              const float* __restrict__ wproj, u16* __restrict__ xbf,
              u16* __restrict__ wqv, u16* __restrict__ wpb)
{
    const int i = blockIdx.x * 256 + threadIdx.x;
    if (i < 1572864) {
        const float4 a = ((const float4*)x)[2*i];
        const float4 b = ((const float4*)x)[2*i + 1];
        ((uint4*)xbf)[i] = make_uint4(pack2bf(a.x,a.y), pack2bf(a.z,a.w),
                                      pack2bf(b.x,b.y), pack2bf(b.z,b.w));
    } else if (i < 1572864 + 147456) {
        const int j = i - 1572864;
        const int row = j / 96;
        const int cc  = (j - row * 96) * 8;
        const int srow = row + (row >= 768 ? 768 : 0);
        const float4 a = *(const float4*)&wqkv[(size_t)srow*768 + cc];
        const float4 b = *(const float4*)&wqkv[(size_t)srow*768 + cc + 4];
        *(uint4*)&wqv[(size_t)row*768 + cc] =
            make_uint4(pack2bf(a.x,a.y), pack2bf(a.z,a.w),
                       pack2bf(b.x,b.y), pack2bf(b.z,b.w));
    } else if (i < 1572864 + 147456 + 73728) {
        const int j = i - 1572864 - 147456;
        const float4 a = ((const float4*)wproj)[2*j];
        const float4 b = ((const float4*)wproj)[2*j + 1];
        ((uint4*)wpb)[j] = make_uint4(pack2bf(a.x,a.y), pack2bf(a.z,a.w),
                                      pack2bf(b.x,b.y), pack2bf(b.z,b.w));
    }
}

// =======================================================================
// Shared helper: build this wave's kf[2][8] = bf16 K frags directly from
// qn staged in LDS (Qs, 128B rows, 16B slot s holds global slot s^(row&7)).
// Gram via MFMA using K symmetry: D(col-lane = K-row r, regs = K-col c).
// kf k-map: c = ks*32 + (j>>2)*16 + q*4 + (j&3), q = l>>4 (D-native map).
// exp(fmaf(10,s,-10)), diag->0, f2bf RNE  ==  cost_kernel's exact math ->
// kf values bitwise-identical to the K the old cost_kernel wrote.
// =======================================================================
__device__ __forceinline__ void gram_kf(const char* Qs, const int l,
                                        const int rowb, bf16x8 kf[2][8])
{
    const int q = l >> 4;
    #pragma unroll
    for (int t = 0; t < 2; ++t) {
        const int rb = rowb + t*16 + (l & 15);          // K-row (lane)
        bf16x8 bfr[2];
        #pragma unroll
        for (int kk = 0; kk < 2; ++kk)
            bfr[kk] = *(const bf16x8*)(Qs + rb*128 + ((kk*64 + q*16) ^ ((rb & 7) << 4)));
        #pragma unroll
        for (int ks = 0; ks < 8; ++ks) {
            f32x4 d0 = {0.f,0.f,0.f,0.f}, d1 = {0.f,0.f,0.f,0.f};
            {
                const int ra = (ks*2)*16 + (l & 15);
                #pragma unroll
                for (int kk = 0; kk < 2; ++kk) {
                    const bf16x8 af = *(const bf16x8*)(Qs + ra*128 + ((kk*64 + q*16) ^ ((ra & 7) << 4)));
                    d0 = __builtin_amdgcn_mfma_f32_16x16x32_bf16(af, bfr[kk], d0, 0, 0, 0);
                }
            }
            {
                const int ra = (ks*2 + 1)*16 + (l & 15);
                #pragma unroll
                for (int kk = 0; kk < 2; ++kk) {
                    const bf16x8 af = *(const bf16x8*)(Qs + ra*128 + ((kk*64 + q*16) ^ ((ra & 7) << 4)));
                    d1 = __builtin_amdgcn_mfma_f32_16x16x32_bf16(af, bfr[kk], d1, 0, 0, 0);
                }
            }
            float km[8];
            #pragma unroll
            for (int rr = 0; rr < 4; ++rr) {
                const int c0 = ks*32 + q*4 + rr;
                km[rr]   = (c0 == rb) ? 0.f : __expf(fmaf(10.f, d0[rr], -10.f));
                const int c1 = ks*32 + 16 + q*4 + rr;
                km[4+rr] = (c1 == rb) ? 0.f : __expf(fmaf(10.f, d1[rr], -10.f));
            }
            uint4 kw = make_uint4(pack2bf(km[0],km[1]), pack2bf(km[2],km[3]),
                                  pack2bf(km[4],km[5]), pack2bf(km[6],km[7]));
            kf[t][ks] = *(const bf16x8*)&kw;
        }
    }
}

// =======================================================================
// K0 (widened tile): q+v projection + FUSED q-normalize. (R18-exact)
// =======================================================================
__global__ __launch_bounds__(256, 3)
void gemm_qkv_mfma(const u16* __restrict__ xbf, const u16* __restrict__ wqv,
                   u16* __restrict__ qnbf, u16* __restrict__ vbfT)
{
    __shared__ u16 As[128*64];     // 16 KB  A panel (x rows)
    __shared__ u16 Bq[128*64];     // 16 KB  q-col panel
    __shared__ u16 Bv[128*64];     // 16 KB  v-col panel
    const int m0 = blockIdx.x * 128;
    const int bj = blockIdx.y;                      // 0..5
    const int tid = threadIdx.x;
    const int l = tid & 63, w = tid >> 6;
    const int wr = w >> 1, wc = w & 1;

    f32x4 accq[4][4], accv[4][4];
    #pragma unroll
    for (int i = 0; i < 4; ++i)
        #pragma unroll
        for (int j = 0; j < 4; ++j) {
            accq[i][j] = (f32x4){0.f,0.f,0.f,0.f};
            accv[i][j] = (f32x4){0.f,0.f,0.f,0.f};
        }

    const char* Ar  = (const char*)xbf + (size_t)m0*1536;
    const char* Bqr = (const char*)wqv + (size_t)(bj*128)*1536;
    const char* Bvr = (const char*)wqv + (size_t)(768 + bj*128)*1536;
    char* Asb = (char*)As;
    char* Bqb = (char*)Bq;
    char* Bvb = (char*)Bv;
    const int co = 16 * ((l & 7) ^ (l >> 3));
    const size_t rstep = (size_t)(l >> 3) * 1536;
    const int rsw = (l & 7) << 4;

    for (int k0 = 0; k0 < 1536; k0 += 128) {
        #pragma unroll
        for (int i = 0; i < 4; ++i) {
            const int rb = i*32 + w*8;
            const size_t goff = (size_t)rb*1536 + rstep + k0 + co;
            gload_lds16(Ar  + goff, Asb + i*4096 + w*1024);
            gload_lds16(Bqr + goff, Bqb + i*4096 + w*1024);
            gload_lds16(Bvr + goff, Bvb + i*4096 + w*1024);
        }
        __syncthreads();
        #pragma unroll
        for (int kk = 0; kk < 2; ++kk) {
            const int coff = (kk*64 + ((l >> 4) << 4)) ^ rsw;
            bf16x8 af[4], bq[4], bv[4];
            #pragma unroll
            for (int mi = 0; mi < 4; ++mi) {
                const int rowA = wr*64 + mi*16 + (l & 15);
                af[mi] = *(const bf16x8*)(Asb + rowA*128 + coff);
                const int rowB = wc*64 + mi*16 + (l & 15);
                bq[mi] = *(const bf16x8*)(Bqb + rowB*128 + coff);
                bv[mi] = *(const bf16x8*)(Bvb + rowB*128 + coff);
            }
            #pragma unroll
            for (int mi = 0; mi < 4; ++mi)
                #pragma unroll
                for (int nj = 0; nj < 4; ++nj)
                    accq[mi][nj] = __builtin_amdgcn_mfma_f32_16x16x32_bf16(
                                       af[mi], bq[nj], accq[mi][nj], 0, 0, 0);
            #pragma unroll
            for (int mi = 0; mi < 4; ++mi)
                #pragma unroll
                for (int nj = 0; nj < 4; ++nj)
                    accv[mi][nj] = __builtin_amdgcn_mfma_f32_16x16x32_bf16(
                                       af[mi], bv[nj], accv[mi][nj], 0, 0, 0);
        }
        __syncthreads();
    }

    const int rbase = m0 + wr*64 + ((l >> 4) << 2);
    {
        const int h = 2*bj + wc;
        #pragma unroll
        for (int mi = 0; mi < 4; ++mi)
            #pragma unroll
            for (int rr = 0; rr < 4; ++rr) {
                float s =      accq[mi][0][rr]*accq[mi][0][rr];
                s = fmaf(accq[mi][1][rr], accq[mi][1][rr], s);
                s = fmaf(accq[mi][2][rr], accq[mi][2][rr], s);
                s = fmaf(accq[mi][3][rr], accq[mi][3][rr], s);
                #pragma unroll
                for (int off = 1; off < 16; off <<= 1) s += __shfl_xor(s, off);
                const float inv = 1.0f / (sqrtf(s) + 1e-8f);
                const int m = rbase + mi*16 + rr;
                const int b_ = m >> 8, n_ = m & 255;
                u16* row = qnbf + ((((size_t)b_*12 + h) << 8) + n_)*64;
                #pragma unroll
                for (int nj = 0; nj < 4; ++nj)
                    row[nj*16 + (l & 15)] = f2bf(accq[mi][nj][rr] * inv);
            }
    }
    {
        const int colb = bj*128 + wc*64;
        #pragma unroll
        for (int mi = 0; mi < 4; ++mi)
            #pragma unroll
            for (int nj = 0; nj < 4; ++nj) {
                const int col = colb + nj*16 + (l & 15);
                const int h = col >> 6, d = col & 63;
                const int m = rbase + mi*16;
                const int b_ = m >> 8, n_ = m & 255;
                uint2 o = make_uint2(pack2bf(accv[mi][nj][0], accv[mi][nj][1]),
                                     pack2bf(accv[mi][nj][2], accv[mi][nj][3]));
                *(uint2*)&vbfT[(((size_t)b_*12 + h)*64 + d)*256 + n_] = o;
            }
    }
}

// =======================================================================
// K5 (widened tile): out = ctx @ w_proj^T + b_proj. (R18-exact)
// =======================================================================
__global__ __launch_bounds__(256, 2)
void gemm_proj_mfma(const u16* __restrict__ ctxb, const u16* __restrict__ wpb,
                    const float* __restrict__ bias, float* __restrict__ out)
{
    __shared__ u16 As[128*64];
    __shared__ u16 B1[128*64];
    __shared__ u16 B2[128*64];
    const int m0 = blockIdx.x * 128;
    const int n0 = blockIdx.y * 256;
    const int tid = threadIdx.x;
    const int l = tid & 63, w = tid >> 6;
    const int wr = w >> 1, wc = w & 1;

    f32x4 acc1[4][4], acc2[4][4];
    #pragma unroll
    for (int i = 0; i < 4; ++i)
        #pragma unroll
        for (int j = 0; j < 4; ++j) {
            acc1[i][j] = (f32x4){0.f,0.f,0.f,0.f};
            acc2[i][j] = (f32x4){0.f,0.f,0.f,0.f};
        }

    const char* Ar  = (const char*)ctxb + (size_t)m0*1536;
    const char* B1r = (const char*)wpb + (size_t)n0*1536;
    const char* B2r = (const char*)wpb + (size_t)(n0 + 128)*1536;
    char* Asb = (char*)As;
    char* B1b = (char*)B1;
    char* B2b = (char*)B2;
    const int co = 16 * ((l & 7) ^ (l >> 3));
    const size_t rstep = (size_t)(l >> 3) * 1536;
    const int rsw = (l & 7) << 4;

    for (int k0 = 0; k0 < 1536; k0 += 128) {
        #pragma unroll
        for (int i = 0; i < 4; ++i) {
            const int rb = i*32 + w*8;
            const size_t goff = (size_t)rb*1536 + rstep + k0 + co;
            gload_lds16(Ar  + goff, Asb + i*4096 + w*1024);
            gload_lds16(B1r + goff, B1b + i*4096 + w*1024);
            gload_lds16(B2r + goff, B2b + i*4096 + w*1024);
        }
        __syncthreads();
        #pragma unroll
        for (int kk = 0; kk < 2; ++kk) {
            const int coff = (kk*64 + ((l >> 4) << 4)) ^ rsw;
            bf16x8 af[4], b1[4], b2[4];
            #pragma unroll
            for (int mi = 0; mi < 4; ++mi) {
                const int rowA = wr*64 + mi*16 + (l & 15);
                af[mi] = *(const bf16x8*)(Asb + rowA*128 + coff);
                const int rowB = wc*64 + mi*16 + (l & 15);
                b1[mi] = *(const bf16x8*)(B1b + rowB*128 + coff);
                b2[mi] = *(const bf16x8*)(B2b + rowB*128 + coff);
            }
            #pragma unroll
            for (int mi = 0; mi < 4; ++mi)
                #pragma unroll
                for (int nj = 0; nj < 4; ++nj)
                    acc1[mi][nj] = __builtin_amdgcn_mfma_f32_16x16x32_bf16(
                                       af[mi], b1[nj], acc1[mi][nj], 0, 0, 0);
            #pragma unroll
            for (int mi = 0; mi < 4; ++mi)
                #pragma unroll
                for (int nj = 0; nj < 4; ++nj)
                    acc2[mi][nj] = __builtin_amdgcn_mfma_f32_16x16x32_bf16(
                                       af[mi], b2[nj], acc2[mi][nj], 0, 0, 0);
        }
        __syncthreads();
    }

    const int rbase = m0 + wr*64 + ((l >> 4) << 2);
    #pragma unroll
    for (int mi = 0; mi < 4; ++mi)
        #pragma unroll
        for (int nj = 0; nj < 4; ++nj) {
            const int col = n0 + wc*64 + nj*16 + (l & 15);
            const float bv = bias[col];
            #pragma unroll
            for (int rr = 0; rr < 4; ++rr) {
                const int m = rbase + mi*16 + rr;
                out[(size_t)m*768 + col] = acc1[mi][nj][rr] + bv;
            }
        }
    #pragma unroll
    for (int mi = 0; mi < 4; ++mi)
        #pragma unroll
        for (int nj = 0; nj < 4; ++nj) {
            const int col = n0 + 128 + wc*64 + nj*16 + (l & 15);
            const float bv = bias[col];
            #pragma unroll
            for (int rr = 0; rr < 4; ++rr) {
                const int m = rbase + mi*16 + rr;
                out[(size_t)m*768 + col] = acc2[mi][nj][rr] + bv;
            }
        }
}

// =======================================================================
// K3 (fused cost+sinkhorn): per (b,h), 512 thr. Stage qn (32 KB, swizzled),
// build kf via gram_kf (no K global traffic), then R15-exact phase 1+2
// with k-map-adapted xf / vv loads. Writes u, v, tmax.
// =======================================================================
__global__ __launch_bounds__(512, 2)
void sinkhorn_kernel(const u16* __restrict__ qnbf, float* __restrict__ ubuf,
                     float* __restrict__ vbuf, float* __restrict__ tmaxbuf)
{
    __shared__ u16 Qs[256*64];       // 32 KB qn, slot s of row r holds slot s^(r&7)
    __shared__ __align__(16) float xv[256];
    __shared__ __align__(16) float usave[256];
    __shared__ __align__(16) u16   xbf[256];
    __shared__ float pmax[8];
    const int bh  = blockIdx.x;
    const int tid = threadIdx.x;
    const int l = tid & 63, w = tid >> 6;
    const int rowb = w * 32;

    // ---- stage qn (pre-swizzled source, linear dest)
    {
        const char* src = (const char*)(qnbf + (size_t)bh * 16384);
        const int s = tid & 7;
        #pragma unroll
        for (int i = 0; i < 4; ++i) {
            const int row = i*64 + (tid >> 3);
            gload_lds16(src + row*128 + ((s ^ (row & 7)) << 4), (char*)Qs + i*8192 + tid*16);
        }
    }
    if (tid < 256) xbf[tid] = 0x3f80;    // bf16(1.0)
    __syncthreads();

    // ---- build kf from gram (K bf16 values == old cost_kernel output)
    bf16x8 kf[2][8];
    gram_kf((const char*)Qs, l, rowb, kf);

    // ---- Phase 1: 20 half-iterations, ONE barrier each
    for (int it = 0; it < 20; ++it) {
        f32x4 a0a = {0.f,0.f,0.f,0.f}, a0b = {0.f,0.f,0.f,0.f};
        f32x4 a1a = {0.f,0.f,0.f,0.f}, a1b = {0.f,0.f,0.f,0.f};
        #pragma unroll
        for (int ks = 0; ks < 8; ++ks) {
            const char* xb = (const char*)xbf + ks*64 + ((l >> 4) << 3);
            const uint2 lo = *(const uint2*)xb;
            const uint2 hi = *(const uint2*)(xb + 32);
            uint4 xw4 = make_uint4(lo.x, lo.y, hi.x, hi.y);
            const bf16x8 xf = *(const bf16x8*)&xw4;
            if (ks < 4) {
                a0a = __builtin_amdgcn_mfma_f32_16x16x32_bf16(kf[0][ks], xf, a0a, 0, 0, 0);
                a1a = __builtin_amdgcn_mfma_f32_16x16x32_bf16(kf[1][ks], xf, a1a, 0, 0, 0);
            } else {
                a0b = __builtin_amdgcn_mfma_f32_16x16x32_bf16(kf[0][ks], xf, a0b, 0, 0, 0);
                a1b = __builtin_amdgcn_mfma_f32_16x16x32_bf16(kf[1][ks], xf, a1b, 0, 0, 0);
            }
        }
        float xn0[4], xn1[4];
        #pragma unroll
        for (int j = 0; j < 4; ++j) {
            xn0[j] = 0.00390625f * __builtin_amdgcn_rcpf(a0a[j] + a0b[j]);
            xn1[j] = 0.00390625f * __builtin_amdgcn_rcpf(a1a[j] + a1b[j]);
        }
        const u32 xp0 = cvtpk2bf(xn0[0], xn0[1]);
        const u32 xp1 = cvtpk2bf(xn0[2], xn0[3]);
        const u32 xp2 = cvtpk2bf(xn1[0], xn1[1]);
        const u32 xp3 = cvtpk2bf(xn1[2], xn1[3]);
        if ((l & 15) == 0) {
            const int r0 = rowb + ((l >> 4) << 2);
            *(uint2*)&xbf[r0]      = make_uint2(xp0, xp1);
            *(uint2*)&xbf[r0 + 16] = make_uint2(xp2, xp3);
            if (it == 18) {
                *(float4*)&usave[r0]      = make_float4(xn0[0], xn0[1], xn0[2], xn0[3]);
                *(float4*)&usave[r0 + 16] = make_float4(xn1[0], xn1[1], xn1[2], xn1[3]);
            }
            if (it == 19) {
                *(float4*)&xv[r0]      = make_float4(xn0[0], xn0[1], xn0[2], xn0[3]);
                *(float4*)&xv[r0 + 16] = make_float4(xn1[0], xn1[1], xn1[2], xn1[3]);
            }
        }
        __syncthreads();
    }

    // ---- Phase 2: Tmax = u[n] * max_m(K*v)  (k-map adapted vv loads)
    {
        float mx0 = 0.f, mx1 = 0.f;
        #pragma unroll
        for (int ks = 0; ks < 8; ++ks) {
            const int mb = ks*32 + ((l >> 4) << 2);
            const float4 va  = *(const float4*)&xv[mb];
            const float4 vb4 = *(const float4*)&xv[mb + 16];
            const float vv[8] = {va.x, va.y, va.z, va.w, vb4.x, vb4.y, vb4.z, vb4.w};
            #pragma unroll
            for (int j = 0; j < 8; ++j) {
                mx0 = fmaxf(mx0, bf2f((u16)kf[0][ks][j]) * vv[j]);
                mx1 = fmaxf(mx1, bf2f((u16)kf[1][ks][j]) * vv[j]);
            }
        }
        float mx = fmaxf(usave[rowb + (l & 15)] * mx0,
                         usave[rowb + 16 + (l & 15)] * mx1);
        #pragma unroll
        for (int off = 32; off > 0; off >>= 1) mx = fmaxf(mx, __shfl_xor(mx, off));
        if (l == 0) pmax[w] = mx;
    }
    __syncthreads();
    if (tid < 256) {
        ubuf[bh * 256 + tid] = usave[tid];
        vbuf[bh * 256 + tid] = xv[tid];
    }
    if (tid == 0) {
        float tm = pmax[0];
        #pragma unroll
        for (int i = 1; i < 8; ++i) tm = fmaxf(tm, pmax[i]);
        tmaxbuf[bh] = tm;
    }
}

// =======================================================================
// K4 (fused cost+pv): stage qn + Vt, build kf via gram_kf, then P+PV with
// k-map-adapted vv/vf loads and per-4-group diag override.
// =======================================================================
__global__ __launch_bounds__(512, 2)
void pv_kernel(const u16* __restrict__ qnbf, const u16* __restrict__ vbfT,
               const float* __restrict__ ubuf, const float* __restrict__ vbuf,
               const float* __restrict__ tmaxbuf, u16* __restrict__ ctxc)
{
    __shared__ u16 Qs[256*64];       // 32 KB qn (swizzled)
    __shared__ u16 Vt[64*256];       // 32 KB, slot s of row d holds slot s^(d&7)
    __shared__ __align__(16) float xv[256];
    const int bh  = blockIdx.x;
    const int b_ = bh / 12, h_ = bh - b_*12;
    const int tid = threadIdx.x;
    const int l = tid & 63, w = tid >> 6;
    const int rowb = w * 32;

    // ---- stage qn + Vt (both pre-swizzled source, linear dest)
    {
        const char* srcq = (const char*)(qnbf + (size_t)bh * 16384);
        const int sq = tid & 7;
        #pragma unroll
        for (int i = 0; i < 4; ++i) {
            const int row = i*64 + (tid >> 3);
            gload_lds16(srcq + row*128 + ((sq ^ (row & 7)) << 4), (char*)Qs + i*8192 + tid*16);
        }
        const char* srcv = (const char*)(vbfT + (size_t)bh * 16384);
        const int s = l & 31;
        #pragma unroll
        for (int i = 0; i < 4; ++i) {
            const int d = i*16 + w*2 + (l >> 5);
            gload_lds16(srcv + d*512 + ((s ^ (d & 7)) << 4), (char*)Vt + i*8192 + w*1024);
        }
    }
    if (tid < 256) xv[tid] = vbuf[bh*256 + tid];
    const float itmax = 1.0f / tmaxbuf[bh];
    const float u0 = ubuf[bh*256 + rowb + (l & 15)];
    const float u1 = ubuf[bh*256 + rowb + 16 + (l & 15)];
    __syncthreads();                 // Qs + Vt + xv resident

    // ---- build kf from gram
    bf16x8 kf[2][8];
    gram_kf((const char*)Qs, l, rowb, kf);

    // ---- per t-half: P frag -> immediate PV MFMA
    u16* outp = ctxc + ((size_t)b_*256)*768 + h_*64;
    const int q = l >> 4;
    #pragma unroll
    for (int t = 0; t < 2; ++t) {
        const int rown = rowb + t*16 + (l & 15);
        const float an = (t == 0 ? u0 : u1) * itmax * 0.125f;
        float psum = 0.f;
        f32x4 acc0 = {0.f,0.f,0.f,0.f}, acc1 = {0.f,0.f,0.f,0.f};
        f32x4 acc2 = {0.f,0.f,0.f,0.f}, acc3 = {0.f,0.f,0.f,0.f};
        #pragma unroll
        for (int ks = 0; ks < 8; ++ks) {
            const int mb = ks*32 + (q << 2);
            const float4 va  = *(const float4*)&xv[mb];
            const float4 vb4 = *(const float4*)&xv[mb + 16];
            const float vv[8] = {va.x, va.y, va.z, va.w, vb4.x, vb4.y, vb4.z, vb4.w};
            float p[8];
            #pragma unroll
            for (int j = 0; j < 8; ++j)
                p[j] = __expf(an * bf2f((u16)kf[t][ks][j]) * vv[j]);
            const int d0j = rown - mb;                   // lower 4-group
            if (d0j >= 0 && d0j < 4) p[d0j] = 1.13314845f;       // exp(0.125)
            const int d1j = rown - mb - 16;              // upper 4-group
            if (d1j >= 0 && d1j < 4) p[4 + d1j] = 1.13314845f;
            psum += ((p[0]+p[1]) + (p[2]+p[3])) + ((p[4]+p[5]) + (p[6]+p[7]));
            uint4 pwv = make_uint4(cvtpk2bf(p[0], p[1]), cvtpk2bf(p[2], p[3]),
                                   cvtpk2bf(p[4], p[5]), cvtpk2bf(p[6], p[7]));
            const bf16x8 pf = *(const bf16x8*)&pwv;
            const int b0 = ks*64 + (q << 3);             // byte off of m=ks*32+q*4
            #pragma unroll
            for (int dt = 0; dt < 4; ++dt) {
                const int d = dt*16 + (l & 15);
                const int sl0 = (b0 >> 4), re0 = b0 & 15;
                const uint2 lo = *(const uint2*)((char*)Vt + d*512 + ((sl0 ^ (d & 7)) << 4) + re0);
                const int b1 = b0 + 32;
                const int sl1 = (b1 >> 4), re1 = b1 & 15;
                const uint2 hi = *(const uint2*)((char*)Vt + d*512 + ((sl1 ^ (d & 7)) << 4) + re1);
                uint4 vw = make_uint4(lo.x, lo.y, hi.x, hi.y);
                const bf16x8 vf = *(const bf16x8*)&vw;
                if (dt == 0) acc0 = __builtin_amdgcn_mfma_f32_16x16x32_bf16(vf, pf, acc0, 0, 0, 0);
                if (dt == 1) acc1 = __builtin_amdgcn_mfma_f32_16x16x32_bf16(vf, pf, acc1, 0, 0, 0);
                if (dt == 2) acc2 = __builtin_amdgcn_mfma_f32_16x16x32_bf16(vf, pf, acc2, 0, 0, 0);
                if (dt == 3) acc3 = __builtin_amdgcn_mfma_f32_16x16x32_bf16(vf, pf, acc3, 0, 0, 0);
            }
        }
        psum += __shfl_xor(psum, 16);
        psum += __shfl_xor(psum, 32);                  // 4 lanes/row summed
        const float is = 1.0f / psum;
        const int d0 = q << 2;
        uint2 o0 = make_uint2(cvtpk2bf(acc0[0]*is, acc0[1]*is), cvtpk2bf(acc0[2]*is, acc0[3]*is));
        uint2 o1 = make_uint2(cvtpk2bf(acc1[0]*is, acc1[1]*is), cvtpk2bf(acc1[2]*is, acc1[3]*is));
        uint2 o2 = make_uint2(cvtpk2bf(acc2[0]*is, acc2[1]*is), cvtpk2bf(acc2[2]*is, acc2[3]*is));
        uint2 o3 = make_uint2(cvtpk2bf(acc3[0]*is, acc3[1]*is), cvtpk2bf(acc3[2]*is, acc3[3]*is));
        u16* orow = outp + (size_t)rown*768;
        *(uint2*)&orow[d0]      = o0;
        *(uint2*)&orow[16 + d0] = o1;
        *(uint2*)&orow[32 + d0] = o2;
        *(uint2*)&orow[48 + d0] = o3;
    }
}

// =======================================================================
extern "C" void kernel_launch(void* const* d_in, const int* in_sizes, int n_in,
                              void* d_out, int out_size, void* d_ws, size_t ws_size,
                              hipStream_t stream)
{
    (void)in_sizes; (void)n_in; (void)out_size; (void)ws_size;
    const float* x      = (const float*)d_in[0];
    const float* w_qkv  = (const float*)d_in[1];
    const float* w_proj = (const float*)d_in[2];
    const float* b_proj = (const float*)d_in[3];
    float* out = (float*)d_out;

    char* w = (char*)d_ws;
    // workspace layout (bytes):
    u16*   xbf  = (u16*)  (w);                     //  25,165,824  x bf16 [16384][768]
    u16*   wqv  = (u16*)  (w + 25165824);          //   2,359,296  w q+v rows bf16 [1536][768]
    u16*   wpb  = (u16*)  (w + 27525120);          //   1,179,648  w_proj bf16 [768][768]
    u16*   qnbf = (u16*)  (w + 28704768);          //  25,165,824  qn bf16 [768][256][64]
    u16*   vbfT = (u16*)  (w + 79036416);          //  25,165,824  v^T bf16 [768][64][256]
    u16*   ctxc = (u16*)  (w + 104202240);         //  25,165,824  ctx bf16 [64][256][768]
    float* ub   = (float*)(w + 129368064);         //     786,432  u [768][256]
    float* vb   = (float*)(w + 130154496);         //     786,432  v [768][256]
    float* tmx  = (float*)(w + 130940928);         //       3,072  tmax [768]
    // K matrix no longer materialized (recomputed from qn in-register)

    conv_all       <<<dim3(7008),    256, 0, stream>>>(x, w_qkv, w_proj, xbf, wqv, wpb);
    gemm_qkv_mfma  <<<dim3(128, 6),  256, 0, stream>>>(xbf, wqv, qnbf, vbfT);
    sinkhorn_kernel<<<dim3(768),     512, 0, stream>>>(qnbf, ub, vb, tmx);
    pv_kernel      <<<dim3(768),     512, 0, stream>>>(qnbf, vbfT, ub, vb, tmx, ctxc);
    gemm_proj_mfma <<<dim3(128, 3),  256, 0, stream>>>(ctxc, wpb, b_proj, out);
}

// Round 20
// 198.265 us; speedup vs baseline: 1.0468x; 1.0468x over previous
//
#include <hip/hip_runtime.h>

typedef unsigned short u16;
typedef unsigned int   u32;
typedef __attribute__((ext_vector_type(8))) short bf16x8;
typedef __attribute__((ext_vector_type(4))) float f32x4;

// ---------- bf16 helpers (manual, RNE) ----------
__device__ __forceinline__ u16 f2bf(float f) {
    u32 u = __float_as_uint(f);
    u += 0x7fffu + ((u >> 16) & 1u);
    return (u16)(u >> 16);
}
__device__ __forceinline__ float bf2f(u16 s) {
    return __uint_as_float(((u32)s) << 16);
}
__device__ __forceinline__ u32 pack2bf(float f0, float f1) {
    return (u32)f2bf(f0) | ((u32)f2bf(f1) << 16);
}
// HW packed conversion (validated on P/ctx/x-iterate paths only — NOT
// upstream of the exp(10*cos-10) amplifier; see R13 post-mortem)
__device__ __forceinline__ u32 cvtpk2bf(float f0, float f1) {
    u32 r;
    asm("v_cvt_pk_bf16_f32 %0, %1, %2" : "=v"(r) : "v"(f0), "v"(f1));
    return r;
}

__device__ __forceinline__ void gload_lds16(const void* g, void* l) {
    __builtin_amdgcn_global_load_lds(
        (const __attribute__((address_space(1))) u32*)g,
        (__attribute__((address_space(3))) u32*)l, 16, 0, 0);
}

// =======================================================================
// Fused fp32 -> bf16 conversion for ALL three inputs (one launch).
// =======================================================================
__global__ __launch_bounds__(256)
void conv_all(const float* __restrict__ x, const float* __restrict__ wqkv,
              const float* __restrict__ wproj, u16* __restrict__ xbf,
              u16* __restrict__ wqv, u16* __restrict__ wpb)
{
    const int i = blockIdx.x * 256 + threadIdx.x;
    if (i < 1572864) {
        const float4 a = ((const float4*)x)[2*i];
        const float4 b = ((const float4*)x)[2*i + 1];
        ((uint4*)xbf)[i] = make_uint4(pack2bf(a.x,a.y), pack2bf(a.z,a.w),
                                      pack2bf(b.x,b.y), pack2bf(b.z,b.w));
    } else if (i < 1572864 + 147456) {
        const int j = i - 1572864;
        const int row = j / 96;
        const int cc  = (j - row * 96) * 8;
        const int srow = row + (row >= 768 ? 768 : 0);
        const float4 a = *(const float4*)&wqkv[(size_t)srow*768 + cc];
        const float4 b = *(const float4*)&wqkv[(size_t)srow*768 + cc + 4];
        *(uint4*)&wqv[(size_t)row*768 + cc] =
            make_uint4(pack2bf(a.x,a.y), pack2bf(a.z,a.w),
                       pack2bf(b.x,b.y), pack2bf(b.z,b.w));
    } else if (i < 1572864 + 147456 + 73728) {
        const int j = i - 1572864 - 147456;
        const float4 a = ((const float4*)wproj)[2*j];
        const float4 b = ((const float4*)wproj)[2*j + 1];
        ((uint4*)wpb)[j] = make_uint4(pack2bf(a.x,a.y), pack2bf(a.z,a.w),
                                      pack2bf(b.x,b.y), pack2bf(b.z,b.w));
    }
}

// =======================================================================
// K0 (widened tile): q+v projection + FUSED q-normalize, ONE block per
// (m0, bj in 0..5): A-tile staged ONCE per K-step, two B-panels, 64 MFMAs
// per K-step against 2 barriers. launch_bounds(256,3): 48KB LDS x 3 =
// 144KB <= 160KB -> 3 blocks/CU; grid 768 = 256 CU x 3 exactly (no tail).
// =======================================================================
__global__ __launch_bounds__(256, 3)
void gemm_qkv_mfma(const u16* __restrict__ xbf, const u16* __restrict__ wqv,
                   u16* __restrict__ qnbf, u16* __restrict__ vbfT)
{
    __shared__ u16 As[128*64];     // 16 KB  A panel (x rows)
    __shared__ u16 Bq[128*64];     // 16 KB  q-col panel (wqv rows bj*128..)
    __shared__ u16 Bv[128*64];     // 16 KB  v-col panel (wqv rows 768+bj*128..)
    const int m0 = blockIdx.x * 128;
    const int bj = blockIdx.y;                      // 0..5
    const int tid = threadIdx.x;
    const int l = tid & 63, w = tid >> 6;
    const int wr = w >> 1, wc = w & 1;

    f32x4 accq[4][4], accv[4][4];
    #pragma unroll
    for (int i = 0; i < 4; ++i)
        #pragma unroll
        for (int j = 0; j < 4; ++j) {
            accq[i][j] = (f32x4){0.f,0.f,0.f,0.f};
            accv[i][j] = (f32x4){0.f,0.f,0.f,0.f};
        }

    const char* Ar  = (const char*)xbf + (size_t)m0*1536;
    const char* Bqr = (const char*)wqv + (size_t)(bj*128)*1536;
    const char* Bvr = (const char*)wqv + (size_t)(768 + bj*128)*1536;
    char* Asb = (char*)As;
    char* Bqb = (char*)Bq;
    char* Bvb = (char*)Bv;
    const int co = 16 * ((l & 7) ^ (l >> 3));       // swizzled global byte col
    const size_t rstep = (size_t)(l >> 3) * 1536;
    const int rsw = (l & 7) << 4;                   // read-side XOR

    for (int k0 = 0; k0 < 1536; k0 += 128) {        // 12 K-steps of 64 bf16
        #pragma unroll
        for (int i = 0; i < 4; ++i) {
            const int rb = i*32 + w*8;
            const size_t goff = (size_t)rb*1536 + rstep + k0 + co;
            gload_lds16(Ar  + goff, Asb + i*4096 + w*1024);
            gload_lds16(Bqr + goff, Bqb + i*4096 + w*1024);
            gload_lds16(Bvr + goff, Bvb + i*4096 + w*1024);
        }
        __syncthreads();
        #pragma unroll
        for (int kk = 0; kk < 2; ++kk) {
            const int coff = (kk*64 + ((l >> 4) << 4)) ^ rsw;
            bf16x8 af[4], bq[4], bv[4];
            #pragma unroll
            for (int mi = 0; mi < 4; ++mi) {
                const int rowA = wr*64 + mi*16 + (l & 15);
                af[mi] = *(const bf16x8*)(Asb + rowA*128 + coff);
                const int rowB = wc*64 + mi*16 + (l & 15);
                bq[mi] = *(const bf16x8*)(Bqb + rowB*128 + coff);
                bv[mi] = *(const bf16x8*)(Bvb + rowB*128 + coff);
            }
            #pragma unroll
            for (int mi = 0; mi < 4; ++mi)
                #pragma unroll
                for (int nj = 0; nj < 4; ++nj)
                    accq[mi][nj] = __builtin_amdgcn_mfma_f32_16x16x32_bf16(
                                       af[mi], bq[nj], accq[mi][nj], 0, 0, 0);
            #pragma unroll
            for (int mi = 0; mi < 4; ++mi)
                #pragma unroll
                for (int nj = 0; nj < 4; ++nj)
                    accv[mi][nj] = __builtin_amdgcn_mfma_f32_16x16x32_bf16(
                                       af[mi], bv[nj], accv[mi][nj], 0, 0, 0);
        }
        __syncthreads();
    }

    const int rbase = m0 + wr*64 + ((l >> 4) << 2);
    // ---- q epilogue: fused normalize, h = 2*bj + wc
    {
        const int h = 2*bj + wc;                   // wave's 64 q-cols = head h
        #pragma unroll
        for (int mi = 0; mi < 4; ++mi)
            #pragma unroll
            for (int rr = 0; rr < 4; ++rr) {
                float s =      accq[mi][0][rr]*accq[mi][0][rr];
                s = fmaf(accq[mi][1][rr], accq[mi][1][rr], s);
                s = fmaf(accq[mi][2][rr], accq[mi][2][rr], s);
                s = fmaf(accq[mi][3][rr], accq[mi][3][rr], s);
                #pragma unroll
                for (int off = 1; off < 16; off <<= 1) s += __shfl_xor(s, off);
                const float inv = 1.0f / (sqrtf(s) + 1e-8f);
                const int m = rbase + mi*16 + rr;
                const int b_ = m >> 8, n_ = m & 255;
                u16* row = qnbf + ((((size_t)b_*12 + h) << 8) + n_)*64;
                #pragma unroll
                for (int nj = 0; nj < 4; ++nj)
                    row[nj*16 + (l & 15)] = f2bf(accq[mi][nj][rr] * inv);
            }
    }
    // ---- v epilogue: transposed bf16 store, colb = bj*128+wc*64
    {
        const int colb = bj*128 + wc*64;
        #pragma unroll
        for (int mi = 0; mi < 4; ++mi)
            #pragma unroll
            for (int nj = 0; nj < 4; ++nj) {
                const int col = colb + nj*16 + (l & 15);
                const int h = col >> 6, d = col & 63;
                const int m = rbase + mi*16;        // rows m..m+3 (consecutive)
                const int b_ = m >> 8, n_ = m & 255;
                uint2 o = make_uint2(pack2bf(accv[mi][nj][0], accv[mi][nj][1]),
                                     pack2bf(accv[mi][nj][2], accv[mi][nj][3]));
                *(uint2*)&vbfT[(((size_t)b_*12 + h)*64 + d)*256 + n_] = o;
            }
    }
}

// =======================================================================
// K5 (widened tile): out = ctx @ w_proj^T + b_proj. (R17-exact)
// =======================================================================
__global__ __launch_bounds__(256, 2)
void gemm_proj_mfma(const u16* __restrict__ ctxb, const u16* __restrict__ wpb,
                    const float* __restrict__ bias, float* __restrict__ out)
{
    __shared__ u16 As[128*64];     // 16 KB  ctx rows
    __shared__ u16 B1[128*64];     // 16 KB  wpb rows n0..
    __shared__ u16 B2[128*64];     // 16 KB  wpb rows n0+128..
    const int m0 = blockIdx.x * 128;
    const int n0 = blockIdx.y * 256;
    const int tid = threadIdx.x;
    const int l = tid & 63, w = tid >> 6;
    const int wr = w >> 1, wc = w & 1;

    f32x4 acc1[4][4], acc2[4][4];
    #pragma unroll
    for (int i = 0; i < 4; ++i)
        #pragma unroll
        for (int j = 0; j < 4; ++j) {
            acc1[i][j] = (f32x4){0.f,0.f,0.f,0.f};
            acc2[i][j] = (f32x4){0.f,0.f,0.f,0.f};
        }

    const char* Ar  = (const char*)ctxb + (size_t)m0*1536;
    const char* B1r = (const char*)wpb + (size_t)n0*1536;
    const char* B2r = (const char*)wpb + (size_t)(n0 + 128)*1536;
    char* Asb = (char*)As;
    char* B1b = (char*)B1;
    char* B2b = (char*)B2;
    const int co = 16 * ((l & 7) ^ (l >> 3));
    const size_t rstep = (size_t)(l >> 3) * 1536;
    const int rsw = (l & 7) << 4;

    for (int k0 = 0; k0 < 1536; k0 += 128) {
        #pragma unroll
        for (int i = 0; i < 4; ++i) {
            const int rb = i*32 + w*8;
            const size_t goff = (size_t)rb*1536 + rstep + k0 + co;
            gload_lds16(Ar  + goff, Asb + i*4096 + w*1024);
            gload_lds16(B1r + goff, B1b + i*4096 + w*1024);
            gload_lds16(B2r + goff, B2b + i*4096 + w*1024);
        }
        __syncthreads();
        #pragma unroll
        for (int kk = 0; kk < 2; ++kk) {
            const int coff = (kk*64 + ((l >> 4) << 4)) ^ rsw;
            bf16x8 af[4], b1[4], b2[4];
            #pragma unroll
            for (int mi = 0; mi < 4; ++mi) {
                const int rowA = wr*64 + mi*16 + (l & 15);
                af[mi] = *(const bf16x8*)(Asb + rowA*128 + coff);
                const int rowB = wc*64 + mi*16 + (l & 15);
                b1[mi] = *(const bf16x8*)(B1b + rowB*128 + coff);
                b2[mi] = *(const bf16x8*)(B2b + rowB*128 + coff);
            }
            #pragma unroll
            for (int mi = 0; mi < 4; ++mi)
                #pragma unroll
                for (int nj = 0; nj < 4; ++nj)
                    acc1[mi][nj] = __builtin_amdgcn_mfma_f32_16x16x32_bf16(
                                       af[mi], b1[nj], acc1[mi][nj], 0, 0, 0);
            #pragma unroll
            for (int mi = 0; mi < 4; ++mi)
                #pragma unroll
                for (int nj = 0; nj < 4; ++nj)
                    acc2[mi][nj] = __builtin_amdgcn_mfma_f32_16x16x32_bf16(
                                       af[mi], b2[nj], acc2[mi][nj], 0, 0, 0);
        }
        __syncthreads();
    }

    const int rbase = m0 + wr*64 + ((l >> 4) << 2);
    #pragma unroll
    for (int mi = 0; mi < 4; ++mi)
        #pragma unroll
        for (int nj = 0; nj < 4; ++nj) {
            const int col = n0 + wc*64 + nj*16 + (l & 15);
            const float bv = bias[col];
            #pragma unroll
            for (int rr = 0; rr < 4; ++rr) {
                const int m = rbase + mi*16 + rr;
                out[(size_t)m*768 + col] = acc1[mi][nj][rr] + bv;
            }
        }
    #pragma unroll
    for (int mi = 0; mi < 4; ++mi)
        #pragma unroll
        for (int nj = 0; nj < 4; ++nj) {
            const int col = n0 + 128 + wc*64 + nj*16 + (l & 15);
            const float bv = bias[col];
            #pragma unroll
            for (int rr = 0; rr < 4; ++rr) {
                const int m = rbase + mi*16 + rr;
                out[(size_t)m*768 + col] = acc2[mi][nj][rr] + bv;
            }
        }
}

// =======================================================================
// K2: K[n][m] = exp(10*cos(n,m) - 10) off-diag, 0 on diag. (R15-exact)
// =======================================================================
__global__ __launch_bounds__(256)
void cost_kernel(const u16* __restrict__ qnbf, u16* __restrict__ Kmat)
{
    __shared__ u16 Qa[128*64];     // [row][64 k] bf16, slot s holds global slot s^(row&7)
    __shared__ u16 Qb[128*64];
    const int bh = blockIdx.y;
    const int tr = (blockIdx.x >> 1) * 128;
    const int tc = (blockIdx.x & 1) * 128;
    const char* qb = (const char*)(qnbf + (size_t)bh * 16384);
    const int tid = threadIdx.x;
    const int l = tid & 63, w = tid >> 6;
    const int wr = w >> 1, wc = w & 1;

    {
        const int co = ((l & 7) ^ (l >> 3)) << 4;   // inverse-swizzled source slot
        const int rl = l >> 3;
        #pragma unroll
        for (int i = 0; i < 4; ++i) {
            const int ch = i*4 + w;                 // chunk 0..15
            gload_lds16(qb + (size_t)(tr + ch*8 + rl)*128 + co, (char*)Qa + ch*1024);
            gload_lds16(qb + (size_t)(tc + ch*8 + rl)*128 + co, (char*)Qb + ch*1024);
        }
    }
    __syncthreads();

    f32x4 acc[4][4];
    #pragma unroll
    for (int i = 0; i < 4; ++i)
        #pragma unroll
        for (int j = 0; j < 4; ++j) acc[i][j] = (f32x4){0.f,0.f,0.f,0.f};

    bf16x8 af[2][4], bfr[2][4];
    #pragma unroll
    for (int kk = 0; kk < 2; ++kk) {
        const int kb = kk*64 + ((l >> 4) << 4);
        #pragma unroll
        for (int f = 0; f < 4; ++f) {
            const int ra = wr*64 + f*16 + (l & 15);
            af[kk][f]  = *(const bf16x8*)((char*)Qa + ra*128 + (kb ^ ((ra & 7) << 4)));
            const int rb = wc*64 + f*16 + (l & 15);
            bfr[kk][f] = *(const bf16x8*)((char*)Qb + rb*128 + (kb ^ ((rb & 7) << 4)));
        }
    }
    #pragma unroll
    for (int mi = 0; mi < 4; ++mi)
        #pragma unroll
        for (int nj = 0; nj < 4; ++nj) {
            acc[mi][nj] = __builtin_amdgcn_mfma_f32_16x16x32_bf16(
                              af[0][mi], bfr[0][nj], acc[mi][nj], 0, 0, 0);
            acc[mi][nj] = __builtin_amdgcn_mfma_f32_16x16x32_bf16(
                              af[1][mi], bfr[1][nj], acc[mi][nj], 0, 0, 0);
        }

    u16* Kb = Kmat + (size_t)bh * 65536;
    #pragma unroll
    for (int mi = 0; mi < 4; ++mi)
        #pragma unroll
        for (int nj = 0; nj < 4; ++nj) {
            const int gr0 = tr + wr*64 + mi*16 + ((l >> 4) << 2);
            const int gc  = tc + wc*64 + nj*16 + (l & 15);
            #pragma unroll
            for (int rr = 0; rr < 4; ++rr) {
                const int gr = gr0 + rr;
                const float s = acc[mi][nj][rr];
                const float km = (gr == gc) ? 0.f : __expf(fmaf(10.f, s, -10.f));
                Kb[(size_t)gr * 256 + gc] = f2bf(km);
            }
        }
}

// =======================================================================
// K3 (split A): Sinkhorn iterations + Tmax only. (R15-exact)
// =======================================================================
__global__ __launch_bounds__(512, 2)
void sinkhorn_kernel(const u16* __restrict__ Kmat, float* __restrict__ ubuf,
                     float* __restrict__ vbuf, float* __restrict__ tmaxbuf)
{
    __shared__ __align__(16) float xv[256];
    __shared__ __align__(16) float usave[256];
    __shared__ __align__(16) u16   xbf[256];
    __shared__ float pmax[8];
    const int bh  = blockIdx.x;
    const int tid = threadIdx.x;
    const int l = tid & 63, w = tid >> 6;
    const int rowb = w * 32;
    const char* Kg = (const char*)(Kmat + (size_t)bh * 65536);

    bf16x8 kf[2][8];
    {
        const char* kb0 = Kg + (size_t)(rowb + (l & 15)) * 512 + ((l >> 4) << 4);
        #pragma unroll
        for (int t = 0; t < 2; ++t)
            #pragma unroll
            for (int ks = 0; ks < 8; ++ks)
                kf[t][ks] = *(const bf16x8*)(kb0 + t*8192 + ks*64);
    }
    if (tid < 256) xbf[tid] = 0x3f80;    // bf16(1.0)
    __syncthreads();

    for (int it = 0; it < 20; ++it) {
        f32x4 a0a = {0.f,0.f,0.f,0.f}, a0b = {0.f,0.f,0.f,0.f};
        f32x4 a1a = {0.f,0.f,0.f,0.f}, a1b = {0.f,0.f,0.f,0.f};
        #pragma unroll
        for (int ks = 0; ks < 4; ++ks) {
            const bf16x8 xf = *(const bf16x8*)((const char*)xbf + ks*64 + ((l >> 4) << 4));
            a0a = __builtin_amdgcn_mfma_f32_16x16x32_bf16(kf[0][ks], xf, a0a, 0, 0, 0);
            a1a = __builtin_amdgcn_mfma_f32_16x16x32_bf16(kf[1][ks], xf, a1a, 0, 0, 0);
        }
        #pragma unroll
        for (int ks = 4; ks < 8; ++ks) {
            const bf16x8 xf = *(const bf16x8*)((const char*)xbf + ks*64 + ((l >> 4) << 4));
            a0b = __builtin_amdgcn_mfma_f32_16x16x32_bf16(kf[0][ks], xf, a0b, 0, 0, 0);
            a1b = __builtin_amdgcn_mfma_f32_16x16x32_bf16(kf[1][ks], xf, a1b, 0, 0, 0);
        }
        float xn0[4], xn1[4];
        #pragma unroll
        for (int j = 0; j < 4; ++j) {
            xn0[j] = 0.00390625f * __builtin_amdgcn_rcpf(a0a[j] + a0b[j]);
            xn1[j] = 0.00390625f * __builtin_amdgcn_rcpf(a1a[j] + a1b[j]);
        }
        const u32 xp0 = cvtpk2bf(xn0[0], xn0[1]);
        const u32 xp1 = cvtpk2bf(xn0[2], xn0[3]);
        const u32 xp2 = cvtpk2bf(xn1[0], xn1[1]);
        const u32 xp3 = cvtpk2bf(xn1[2], xn1[3]);
        if ((l & 15) == 0) {
            const int r0 = rowb + ((l >> 4) << 2);
            *(uint2*)&xbf[r0]      = make_uint2(xp0, xp1);
            *(uint2*)&xbf[r0 + 16] = make_uint2(xp2, xp3);
            if (it == 18) {
                *(float4*)&usave[r0]      = make_float4(xn0[0], xn0[1], xn0[2], xn0[3]);
                *(float4*)&usave[r0 + 16] = make_float4(xn1[0], xn1[1], xn1[2], xn1[3]);
            }
            if (it == 19) {
                *(float4*)&xv[r0]      = make_float4(xn0[0], xn0[1], xn0[2], xn0[3]);
                *(float4*)&xv[r0 + 16] = make_float4(xn1[0], xn1[1], xn1[2], xn1[3]);
            }
        }
        __syncthreads();
    }

    {
        float mx0 = 0.f, mx1 = 0.f;
        #pragma unroll
        for (int ks = 0; ks < 8; ++ks) {
            const int mbase = ks*32 + ((l >> 4) << 3);
            const float4 va  = *(const float4*)&xv[mbase];
            const float4 vb4 = *(const float4*)&xv[mbase + 4];
            const float vv[8] = {va.x, va.y, va.z, va.w, vb4.x, vb4.y, vb4.z, vb4.w};
            #pragma unroll
            for (int j = 0; j < 8; ++j) {
                mx0 = fmaxf(mx0, bf2f((u16)kf[0][ks][j]) * vv[j]);
                mx1 = fmaxf(mx1, bf2f((u16)kf[1][ks][j]) * vv[j]);
            }
        }
        float mx = fmaxf(usave[rowb + (l & 15)] * mx0,
                         usave[rowb + 16 + (l & 15)] * mx1);
        #pragma unroll
        for (int off = 32; off > 0; off >>= 1) mx = fmaxf(mx, __shfl_xor(mx, off));
        if (l == 0) pmax[w] = mx;
    }
    __syncthreads();
    if (tid < 256) {
        ubuf[bh * 256 + tid] = usave[tid];
        vbuf[bh * 256 + tid] = xv[tid];
    }
    if (tid == 0) {
        float tm = pmax[0];
        #pragma unroll
        for (int i = 1; i < 8; ++i) tm = fmaxf(tm, pmax[i]);
        tmaxbuf[bh] = tm;
    }
}

// =======================================================================
// K4 (split B): P + PV. (R15-exact)
// =======================================================================
__global__ __launch_bounds__(512, 2)
void pv_kernel(const u16* __restrict__ Kmat, const u16* __restrict__ vbfT,
               const float* __restrict__ ubuf, const float* __restrict__ vbuf,
               const float* __restrict__ tmaxbuf, u16* __restrict__ ctxc)
{
    __shared__ u16 Vt[64*256];       // 32 KB, slot s of row d holds global slot s^(d&7)
    __shared__ __align__(16) float xv[256];
    const int bh  = blockIdx.x;
    const int b_ = bh / 12, h_ = bh - b_*12;
    const int tid = threadIdx.x;
    const int l = tid & 63, w = tid >> 6;
    const int rowb = w * 32;
    const char* Kg = (const char*)(Kmat + (size_t)bh * 65536);

    {
        const char* src = (const char*)(vbfT + (size_t)bh * 16384);
        char* dst = (char*)Vt;
        const int s = l & 31;
        #pragma unroll
        for (int i = 0; i < 4; ++i) {
            const int d = i*16 + w*2 + (l >> 5);
            gload_lds16(src + d*512 + ((s ^ (d & 7)) << 4), dst + i*8192 + w*1024);
        }
    }
    if (tid < 256) xv[tid] = vbuf[bh*256 + tid];

    bf16x8 kf[2][8];
    {
        const char* kb0 = Kg + (size_t)(rowb + (l & 15)) * 512 + ((l >> 4) << 4);
        #pragma unroll
        for (int t = 0; t < 2; ++t)
            #pragma unroll
            for (int ks = 0; ks < 8; ++ks)
                kf[t][ks] = *(const bf16x8*)(kb0 + t*8192 + ks*64);
    }
    const float itmax = 1.0f / tmaxbuf[bh];
    const float u0 = ubuf[bh*256 + rowb + (l & 15)];
    const float u1 = ubuf[bh*256 + rowb + 16 + (l & 15)];
    __syncthreads();                 // Vt + xv resident

    u16* outp = ctxc + ((size_t)b_*256)*768 + h_*64;
    #pragma unroll
    for (int t = 0; t < 2; ++t) {
        const int rown = rowb + t*16 + (l & 15);
        const float an = (t == 0 ? u0 : u1) * itmax * 0.125f;
        float psum = 0.f;
        f32x4 acc0 = {0.f,0.f,0.f,0.f}, acc1 = {0.f,0.f,0.f,0.f};
        f32x4 acc2 = {0.f,0.f,0.f,0.f}, acc3 = {0.f,0.f,0.f,0.f};
        #pragma unroll
        for (int ks = 0; ks < 8; ++ks) {
            const int mbase = ks*32 + ((l >> 4) << 3);
            const float4 va  = *(const float4*)&xv[mbase];
            const float4 vb4 = *(const float4*)&xv[mbase + 4];
            const float vv[8] = {va.x, va.y, va.z, va.w, vb4.x, vb4.y, vb4.z, vb4.w};
            float p[8];
            #pragma unroll
            for (int j = 0; j < 8; ++j)
                p[j] = __expf(an * bf2f((u16)kf[t][ks][j]) * vv[j]);
            const int dj = rown - mbase;
            if (dj >= 0 && dj < 8) p[dj] = 1.13314845f;     // exp(0.125)
            psum += ((p[0]+p[1]) + (p[2]+p[3])) + ((p[4]+p[5]) + (p[6]+p[7]));
            uint4 pwv = make_uint4(cvtpk2bf(p[0], p[1]), cvtpk2bf(p[2], p[3]),
                                   cvtpk2bf(p[4], p[5]), cvtpk2bf(p[6], p[7]));
            const bf16x8 pf = *(const bf16x8*)&pwv;
            const int bc = ks*64 + ((l >> 4) << 4);
            {
                const int d = (l & 15);
                const bf16x8 vf = *(const bf16x8*)((char*)Vt + d*512 + (bc ^ ((d & 7) << 4)));
                acc0 = __builtin_amdgcn_mfma_f32_16x16x32_bf16(vf, pf, acc0, 0, 0, 0);
            }
            {
                const int d = 16 + (l & 15);
                const bf16x8 vf = *(const bf16x8*)((char*)Vt + d*512 + (bc ^ ((d & 7) << 4)));
                acc1 = __builtin_amdgcn_mfma_f32_16x16x32_bf16(vf, pf, acc1, 0, 0, 0);
            }
            {
                const int d = 32 + (l & 15);
                const bf16x8 vf = *(const bf16x8*)((char*)Vt + d*512 + (bc ^ ((d & 7) << 4)));
                acc2 = __builtin_amdgcn_mfma_f32_16x16x32_bf16(vf, pf, acc2, 0, 0, 0);
            }
            {
                const int d = 48 + (l & 15);
                const bf16x8 vf = *(const bf16x8*)((char*)Vt + d*512 + (bc ^ ((d & 7) << 4)));
                acc3 = __builtin_amdgcn_mfma_f32_16x16x32_bf16(vf, pf, acc3, 0, 0, 0);
            }
        }
        psum += __shfl_xor(psum, 16);
        psum += __shfl_xor(psum, 32);                  // 4 lanes/row summed
        const float is = 1.0f / psum;
        const int d0 = (l >> 4) << 2;
        uint2 o0 = make_uint2(cvtpk2bf(acc0[0]*is, acc0[1]*is), cvtpk2bf(acc0[2]*is, acc0[3]*is));
        uint2 o1 = make_uint2(cvtpk2bf(acc1[0]*is, acc1[1]*is), cvtpk2bf(acc1[2]*is, acc1[3]*is));
        uint2 o2 = make_uint2(cvtpk2bf(acc2[0]*is, acc2[1]*is), cvtpk2bf(acc2[2]*is, acc2[3]*is));
        uint2 o3 = make_uint2(cvtpk2bf(acc3[0]*is, acc3[1]*is), cvtpk2bf(acc3[2]*is, acc3[3]*is));
        u16* orow = outp + (size_t)rown*768;
        *(uint2*)&orow[d0]      = o0;
        *(uint2*)&orow[16 + d0] = o1;
        *(uint2*)&orow[32 + d0] = o2;
        *(uint2*)&orow[48 + d0] = o3;
    }
}

// =======================================================================
extern "C" void kernel_launch(void* const* d_in, const int* in_sizes, int n_in,
                              void* d_out, int out_size, void* d_ws, size_t ws_size,
                              hipStream_t stream)
{
    (void)in_sizes; (void)n_in; (void)out_size; (void)ws_size;
    const float* x      = (const float*)d_in[0];
    const float* w_qkv  = (const float*)d_in[1];
    const float* w_proj = (const float*)d_in[2];
    const float* b_proj = (const float*)d_in[3];
    float* out = (float*)d_out;

    char* w = (char*)d_ws;
    // workspace layout (bytes):
    u16*   xbf  = (u16*)  (w);                     //  25,165,824  x bf16 [16384][768]
    u16*   wqv  = (u16*)  (w + 25165824);          //   2,359,296  w q+v rows bf16 [1536][768]
    u16*   wpb  = (u16*)  (w + 27525120);          //   1,179,648  w_proj bf16 [768][768]
    u16*   qnbf = (u16*)  (w + 28704768);          //  25,165,824  qn bf16 [768][256][64]
    u16*   vbfT = (u16*)  (w + 79036416);          //  25,165,824  v^T bf16 [768][64][256]
    u16*   ctxc = (u16*)  (w + 104202240);         //  25,165,824  ctx bf16 [64][256][768]
    float* ub   = (float*)(w + 129368064);         //     786,432  u [768][256]
    float* vb   = (float*)(w + 130154496);         //     786,432  v [768][256]
    float* tmx  = (float*)(w + 130940928);         //       3,072  tmax [768]
    u16*   Km   = (u16*)  (w + 130944000);         // 100,663,296  K bf16 [768][256][256]
    // total ~231.6 MB

    conv_all       <<<dim3(7008),    256, 0, stream>>>(x, w_qkv, w_proj, xbf, wqv, wpb);
    gemm_qkv_mfma  <<<dim3(128, 6),  256, 0, stream>>>(xbf, wqv, qnbf, vbfT);
    cost_kernel    <<<dim3(4, 768),  256, 0, stream>>>(qnbf, Km);
    sinkhorn_kernel<<<dim3(768),     512, 0, stream>>>(Km, ub, vb, tmx);
    pv_kernel      <<<dim3(768),     512, 0, stream>>>(Km, vbfT, ub, vb, tmx, ctxc);
    gemm_proj_mfma <<<dim3(128, 3),  256, 0, stream>>>(ctxc, wpb, b_proj, out);
}